// Round 4
// baseline (350.930 us; speedup 1.0000x reference)
//
#include <hip/hip_runtime.h>
#include <hip/hip_bf16.h>
#include <math.h>

#define NP   8192
#define CD   512
#define KD   64
#define TWON 16384
#define CC   1024   // virtual contraction: [f | f^2]

typedef __attribute__((ext_vector_type(8))) short short8;
typedef __attribute__((ext_vector_type(4))) float f32x4;

__device__ __forceinline__ void split_bf16(float x, __hip_bfloat16& h, __hip_bfloat16& l) {
    h = __float2bfloat16(x);
    l = __float2bfloat16(x - __bfloat162float(h));
}

// ---------------------------------------------------------------------------
// K0: prep. VTT[k][cc] (bf16 hi/lo), cc<512 -> 2*m*inv2 (pairs with f),
// cc>=512 -> -inv2 (pairs with f^2). cst[k] = sum_c m^2*inv2 (fp32).
// dist[n,k] = sum_cc U[n,cc]*VTT[k,cc] - cst[k],  U = [f | f^2]
// ---------------------------------------------------------------------------
__global__ __launch_bounds__(256) void prep_kernel(
    const float* __restrict__ means, const float* __restrict__ scales,
    __hip_bfloat16* __restrict__ VTT_hi, __hip_bfloat16* __restrict__ VTT_lo,
    float* __restrict__ cst)
{
    const int k = blockIdx.x;
    const int t = threadIdx.x;
    __shared__ float red[256];
    float local = 0.f;
    for (int c = t; c < CD; c += 256) {
        float m    = means[k * CD + c];
        float s    = scales[k * CD + c];
        float inv  = 1.0f / s;
        float inv2 = inv * inv;
        __hip_bfloat16 h, l;
        split_bf16(2.0f * m * inv2, h, l);
        VTT_hi[(size_t)k * CC + c] = h;
        VTT_lo[(size_t)k * CC + c] = l;
        split_bf16(-inv2, h, l);
        VTT_hi[(size_t)k * CC + CD + c] = h;
        VTT_lo[(size_t)k * CC + CD + c] = l;
        local += m * m * inv2;
    }
    red[t] = local;
    __syncthreads();
    for (int off = 128; off > 0; off >>= 1) {
        if (t < off) red[t] += red[t + off];
        __syncthreads();
    }
    if (t == 0) cst[k] = red[0];
}

// ---------------------------------------------------------------------------
// K1: phi bf16 [16384][64] via MFMA, zero LDS. Grid 1024: block = 64 rows x
// 16 k-outs (wave = 16-row m-tile). 4 blocks/CU -> 4 waves/SIMD for latency
// hiding. A = f rows split to bf16 hi/lo in-register (linear + squared),
// B = VTT hi/lo (L2-resident). Compensated: AhBh + AhBl + AlBh.
// ---------------------------------------------------------------------------
__global__ __launch_bounds__(256) void phi_kernel(
    const float* __restrict__ f_i, const float* __restrict__ f_j,
    const __hip_bfloat16* __restrict__ VTT_hi,
    const __hip_bfloat16* __restrict__ VTT_lo,
    const float* __restrict__ cst, const float* __restrict__ weights,
    __hip_bfloat16* __restrict__ phi)
{
    const int t = threadIdx.x, lane = t & 63, wave = t >> 6;
    const int q = lane >> 4, m = lane & 15;
    const int base = (blockIdx.x >> 2) * 64 + wave * 16;  // 16-row m-tile
    const int kt   = (blockIdx.x & 3) * 16;               // 16 k-outs
    const bool iside = (base < NP);                       // uniform per block
    const float* frow = iside ? &f_i[(size_t)(base + m) * CD]
                              : &f_j[(size_t)(base + m - NP) * CD];
    const short* BH = (const short*)VTT_hi;
    const short* BL = (const short*)VTT_lo;

    f32x4 acc = (f32x4){0.f, 0.f, 0.f, 0.f};

    for (int ch = 0; ch < 16; ++ch) {
        const int c0 = ch * 32 + q * 8;
        float4 x0 = *(const float4*)&frow[c0];
        float4 x1 = *(const float4*)&frow[c0 + 4];
        float xs[8] = {x0.x, x0.y, x0.z, x0.w, x1.x, x1.y, x1.z, x1.w};
        union { short8 v; __hip_bfloat16 h[8]; } aLh, aLl, aSh, aSl;
        #pragma unroll
        for (int j = 0; j < 8; ++j) {
            __hip_bfloat16 h, l;
            split_bf16(xs[j], h, l);          aLh.h[j] = h; aLl.h[j] = l;
            split_bf16(xs[j] * xs[j], h, l);  aSh.h[j] = h; aSl.h[j] = l;
        }
        const size_t boff = (size_t)(kt + m) * CC + c0;
        short8 bh0 = *(const short8*)&BH[boff];
        short8 bl0 = *(const short8*)&BL[boff];
        short8 bh1 = *(const short8*)&BH[boff + CD];
        short8 bl1 = *(const short8*)&BL[boff + CD];
        acc = __builtin_amdgcn_mfma_f32_16x16x32_bf16(aLh.v, bh0, acc, 0, 0, 0);
        acc = __builtin_amdgcn_mfma_f32_16x16x32_bf16(aLh.v, bl0, acc, 0, 0, 0);
        acc = __builtin_amdgcn_mfma_f32_16x16x32_bf16(aLl.v, bh0, acc, 0, 0, 0);
        acc = __builtin_amdgcn_mfma_f32_16x16x32_bf16(aSh.v, bh1, acc, 0, 0, 0);
        acc = __builtin_amdgcn_mfma_f32_16x16x32_bf16(aSh.v, bl1, acc, 0, 0, 0);
        acc = __builtin_amdgcn_mfma_f32_16x16x32_bf16(aSl.v, bh1, acc, 0, 0, 0);
    }

    // D layout: row (within m-tile) = q*4+r, col (= k-out) = lane&15 = m
    const int kout = kt + m;
    const float cs = cst[kout];
    const float wv = iside ? weights[kout] : 1.0f;
    #pragma unroll
    for (int r = 0; r < 4; ++r) {
        const int row = base + q * 4 + r;
        float ph = expf(acc[r] - cs) * wv;
        phi[(size_t)row * KD + kout] = __float2bfloat16(ph);
    }
}

// ---------------------------------------------------------------------------
// K2: out = phi_i @ phi_j^T via mfma_f32_16x16x32_bf16, zero LDS.
// A-operand = phi_j rows (m-dim = j), B-operand = phi_i rows (n-dim = i)
// so each lane's 4 acc regs are 4 CONSECUTIVE j of one i-row -> dwordx4 store.
// Stores are NONTEMPORAL: out is write-once, keep phi L2-resident.
// Block 128x128 (4 waves x 64x64 quadrant).
// ---------------------------------------------------------------------------
__global__ __launch_bounds__(256) void gemm_kernel(
    const __hip_bfloat16* __restrict__ phi, float* __restrict__ out)
{
    const int t = threadIdx.x, lane = t & 63, wave = t >> 6;
    const int q = lane >> 4, m = lane & 15;
    const int i0 = blockIdx.y * 128 + (wave & 1) * 64;
    const int j0 = blockIdx.x * 128 + (wave >> 1) * 64;
    const short* phiS = (const short*)phi;

    short8 Aj[4][2], Bi[4][2];
    #pragma unroll
    for (int tt = 0; tt < 4; ++tt)
        #pragma unroll
        for (int kh = 0; kh < 2; ++kh) {
            Aj[tt][kh] = *(const short8*)
                &phiS[(size_t)(NP + j0 + tt * 16 + m) * KD + kh * 32 + q * 8];
            Bi[tt][kh] = *(const short8*)
                &phiS[(size_t)(i0 + tt * 16 + m) * KD + kh * 32 + q * 8];
        }

    f32x4 acc[4][4];   // [i-tile][j-tile]
    #pragma unroll
    for (int bt = 0; bt < 4; ++bt)
        #pragma unroll
        for (int at = 0; at < 4; ++at)
            acc[bt][at] = (f32x4){0.f, 0.f, 0.f, 0.f};

    #pragma unroll
    for (int bt = 0; bt < 4; ++bt)
        #pragma unroll
        for (int at = 0; at < 4; ++at) {
            acc[bt][at] = __builtin_amdgcn_mfma_f32_16x16x32_bf16(
                Aj[at][0], Bi[bt][0], acc[bt][at], 0, 0, 0);
            acc[bt][at] = __builtin_amdgcn_mfma_f32_16x16x32_bf16(
                Aj[at][1], Bi[bt][1], acc[bt][at], 0, 0, 0);
        }

    // D: row(q*4+r) = j within at-tile, col(lane&15) = i within bt-tile
    #pragma unroll
    for (int bt = 0; bt < 4; ++bt) {
        const size_t row = (size_t)(i0 + bt * 16 + m);
        #pragma unroll
        for (int at = 0; at < 4; ++at) {
            f32x4* dst = (f32x4*)&out[row * NP + j0 + at * 16 + q * 4];
            __builtin_nontemporal_store(acc[bt][at], dst);
        }
    }
}

// ---------------------------------------------------------------------------
extern "C" void kernel_launch(void* const* d_in, const int* in_sizes, int n_in,
                              void* d_out, int out_size, void* d_ws, size_t ws_size,
                              hipStream_t stream) {
    const float* f_i     = (const float*)d_in[0];
    const float* f_j     = (const float*)d_in[1];
    const float* means   = (const float*)d_in[2];
    const float* scales  = (const float*)d_in[3];
    const float* weights = (const float*)d_in[4];
    float* out = (float*)d_out;

    char* ws = (char*)d_ws;
    __hip_bfloat16* VTT_hi = (__hip_bfloat16*)(ws);            // 64*1024*2 = 128 KB
    __hip_bfloat16* VTT_lo = (__hip_bfloat16*)(ws + 131072);   // 128 KB
    float*          cst    = (float*)(ws + 262144);            // 256 B
    __hip_bfloat16* phi    = (__hip_bfloat16*)(ws + 262400);   // 16384*64*2 = 2 MB

    prep_kernel<<<64, 256, 0, stream>>>(means, scales, VTT_hi, VTT_lo, cst);
    phi_kernel<<<1024, 256, 0, stream>>>(f_i, f_j, VTT_hi, VTT_lo, cst, weights, phi);
    gemm_kernel<<<dim3(64, 64), 256, 0, stream>>>(phi, out);
}

// Round 5
// 328.564 us; speedup vs baseline: 1.0681x; 1.0681x over previous
//
#include <hip/hip_runtime.h>
#include <hip/hip_bf16.h>
#include <math.h>

#define NP   8192
#define CD   512
#define KD   64
#define TWON 16384
#define CC   1024   // virtual contraction: [f | f^2]

typedef __attribute__((ext_vector_type(8))) short short8;
typedef __attribute__((ext_vector_type(4))) float f32x4;

__device__ __forceinline__ void split_bf16(float x, __hip_bfloat16& h, __hip_bfloat16& l) {
    h = __float2bfloat16(x);
    l = __float2bfloat16(x - __bfloat162float(h));
}

// ---------------------------------------------------------------------------
// K0: prep. VTT[k][cc] (bf16 hi/lo), cc<512 -> 2*m*inv2 (pairs with f),
// cc>=512 -> -inv2 (pairs with f^2). cst[k] = sum_c m^2*inv2 (fp32).
// dist[n,k] = sum_cc U[n,cc]*VTT[k,cc] - cst[k],  U = [f | f^2]
// ---------------------------------------------------------------------------
__global__ __launch_bounds__(256) void prep_kernel(
    const float* __restrict__ means, const float* __restrict__ scales,
    __hip_bfloat16* __restrict__ VTT_hi, __hip_bfloat16* __restrict__ VTT_lo,
    float* __restrict__ cst)
{
    const int k = blockIdx.x;
    const int t = threadIdx.x;
    __shared__ float red[256];
    float local = 0.f;
    for (int c = t; c < CD; c += 256) {
        float m    = means[k * CD + c];
        float s    = scales[k * CD + c];
        float inv  = 1.0f / s;
        float inv2 = inv * inv;
        __hip_bfloat16 h, l;
        split_bf16(2.0f * m * inv2, h, l);
        VTT_hi[(size_t)k * CC + c] = h;
        VTT_lo[(size_t)k * CC + c] = l;
        split_bf16(-inv2, h, l);
        VTT_hi[(size_t)k * CC + CD + c] = h;
        VTT_lo[(size_t)k * CC + CD + c] = l;
        local += m * m * inv2;
    }
    red[t] = local;
    __syncthreads();
    for (int off = 128; off > 0; off >>= 1) {
        if (t < off) red[t] += red[t + off];
        __syncthreads();
    }
    if (t == 0) cst[k] = red[0];
}

// ---------------------------------------------------------------------------
// K1: phi bf16 [16384][64] via MFMA, zero LDS. Grid 1024: block = 64 rows x
// 16 k-outs (wave = 16-row m-tile). 4 blocks/CU -> 4 waves/SIMD for latency
// hiding. A = f rows split to bf16 hi/lo in-register (linear + squared),
// B = VTT hi/lo (L2-resident). Compensated: AhBh + AhBl + AlBh.
// ---------------------------------------------------------------------------
__global__ __launch_bounds__(256) void phi_kernel(
    const float* __restrict__ f_i, const float* __restrict__ f_j,
    const __hip_bfloat16* __restrict__ VTT_hi,
    const __hip_bfloat16* __restrict__ VTT_lo,
    const float* __restrict__ cst, const float* __restrict__ weights,
    __hip_bfloat16* __restrict__ phi)
{
    const int t = threadIdx.x, lane = t & 63, wave = t >> 6;
    const int q = lane >> 4, m = lane & 15;
    const int base = (blockIdx.x >> 2) * 64 + wave * 16;  // 16-row m-tile
    const int kt   = (blockIdx.x & 3) * 16;               // 16 k-outs
    const bool iside = (base < NP);                       // uniform per block
    const float* frow = iside ? &f_i[(size_t)(base + m) * CD]
                              : &f_j[(size_t)(base + m - NP) * CD];
    const short* BH = (const short*)VTT_hi;
    const short* BL = (const short*)VTT_lo;

    f32x4 acc = (f32x4){0.f, 0.f, 0.f, 0.f};

    for (int ch = 0; ch < 16; ++ch) {
        const int c0 = ch * 32 + q * 8;
        float4 x0 = *(const float4*)&frow[c0];
        float4 x1 = *(const float4*)&frow[c0 + 4];
        float xs[8] = {x0.x, x0.y, x0.z, x0.w, x1.x, x1.y, x1.z, x1.w};
        union { short8 v; __hip_bfloat16 h[8]; } aLh, aLl, aSh, aSl;
        #pragma unroll
        for (int j = 0; j < 8; ++j) {
            __hip_bfloat16 h, l;
            split_bf16(xs[j], h, l);          aLh.h[j] = h; aLl.h[j] = l;
            split_bf16(xs[j] * xs[j], h, l);  aSh.h[j] = h; aSl.h[j] = l;
        }
        const size_t boff = (size_t)(kt + m) * CC + c0;
        short8 bh0 = *(const short8*)&BH[boff];
        short8 bl0 = *(const short8*)&BL[boff];
        short8 bh1 = *(const short8*)&BH[boff + CD];
        short8 bl1 = *(const short8*)&BL[boff + CD];
        acc = __builtin_amdgcn_mfma_f32_16x16x32_bf16(aLh.v, bh0, acc, 0, 0, 0);
        acc = __builtin_amdgcn_mfma_f32_16x16x32_bf16(aLh.v, bl0, acc, 0, 0, 0);
        acc = __builtin_amdgcn_mfma_f32_16x16x32_bf16(aLl.v, bh0, acc, 0, 0, 0);
        acc = __builtin_amdgcn_mfma_f32_16x16x32_bf16(aSh.v, bh1, acc, 0, 0, 0);
        acc = __builtin_amdgcn_mfma_f32_16x16x32_bf16(aSh.v, bl1, acc, 0, 0, 0);
        acc = __builtin_amdgcn_mfma_f32_16x16x32_bf16(aSl.v, bh1, acc, 0, 0, 0);
    }

    // D layout: row (within m-tile) = q*4+r, col (= k-out) = lane&15 = m
    const int kout = kt + m;
    const float cs = cst[kout];
    const float wv = iside ? weights[kout] : 1.0f;
    #pragma unroll
    for (int r = 0; r < 4; ++r) {
        const int row = base + q * 4 + r;
        float ph = expf(acc[r] - cs) * wv;
        phi[(size_t)row * KD + kout] = __float2bfloat16(ph);
    }
}

// ---------------------------------------------------------------------------
// K2: out = phi_i @ phi_j^T via mfma_f32_16x16x32_bf16. Block 128x128
// (4 waves x 64x64 quadrant), zero LDS in main loop. Epilogue round-trips
// accs through a 64x136 LDS tile (two passes by wave i-parity) so global
// stores are 512 B contiguous per row (full 128 B lines -> no partial-line
// write penalty / RFO).
// ---------------------------------------------------------------------------
#define LDS_PITCH 136
__global__ __launch_bounds__(256) void gemm_kernel(
    const __hip_bfloat16* __restrict__ phi, float* __restrict__ out)
{
    __shared__ float lds[64 * LDS_PITCH];
    const int t = threadIdx.x, lane = t & 63, wave = t >> 6;
    const int q = lane >> 4, m = lane & 15;
    const int ih = wave & 1, jh = wave >> 1;   // wave's quadrant
    const int i0 = blockIdx.y * 128 + ih * 64;
    const int j0 = blockIdx.x * 128 + jh * 64;
    const short* phiS = (const short*)phi;

    short8 Aj[4][2], Bi[4][2];
    #pragma unroll
    for (int tt = 0; tt < 4; ++tt)
        #pragma unroll
        for (int kh = 0; kh < 2; ++kh) {
            Aj[tt][kh] = *(const short8*)
                &phiS[(size_t)(NP + j0 + tt * 16 + m) * KD + kh * 32 + q * 8];
            Bi[tt][kh] = *(const short8*)
                &phiS[(size_t)(i0 + tt * 16 + m) * KD + kh * 32 + q * 8];
        }

    f32x4 acc[4][4];   // [i-tile][j-tile]
    #pragma unroll
    for (int bt = 0; bt < 4; ++bt)
        #pragma unroll
        for (int at = 0; at < 4; ++at)
            acc[bt][at] = (f32x4){0.f, 0.f, 0.f, 0.f};

    #pragma unroll
    for (int bt = 0; bt < 4; ++bt)
        #pragma unroll
        for (int at = 0; at < 4; ++at) {
            acc[bt][at] = __builtin_amdgcn_mfma_f32_16x16x32_bf16(
                Aj[at][0], Bi[bt][0], acc[bt][at], 0, 0, 0);
            acc[bt][at] = __builtin_amdgcn_mfma_f32_16x16x32_bf16(
                Aj[at][1], Bi[bt][1], acc[bt][at], 0, 0, 0);
        }

    // Epilogue. acc[bt][at][r] = out[i0 + bt*16 + m][j0 + at*16 + q*4 + r].
    // Pass p handles block rows [p*64, p*64+64): waves with ih==p dump to
    // LDS [local_i][jh*64 + at*16 + q*4], then ALL threads stream 64 rows
    // out with 32 lanes x float4 = 512 B contiguous per row.
    const size_t orow0 = (size_t)blockIdx.y * 128;
    const int    ocol0 = blockIdx.x * 128;
    #pragma unroll
    for (int p = 0; p < 2; ++p) {
        __syncthreads();
        if (ih == p) {
            #pragma unroll
            for (int bt = 0; bt < 4; ++bt)
                #pragma unroll
                for (int at = 0; at < 4; ++at)
                    *(float4*)&lds[(bt * 16 + m) * LDS_PITCH
                                   + jh * 64 + at * 16 + q * 4] =
                        (float4){acc[bt][at][0], acc[bt][at][1],
                                 acc[bt][at][2], acc[bt][at][3]};
        }
        __syncthreads();
        #pragma unroll
        for (int it = 0; it < 8; ++it) {
            int v  = t + it * 256;        // 0..2047 float4 slots
            int lr = v >> 5;              // 0..63
            int c4 = (v & 31) * 4;        // 0..124
            float4 val = *(const float4*)&lds[lr * LDS_PITCH + c4];
            *(float4*)&out[(orow0 + p * 64 + lr) * NP + ocol0 + c4] = val;
        }
    }
}

// ---------------------------------------------------------------------------
extern "C" void kernel_launch(void* const* d_in, const int* in_sizes, int n_in,
                              void* d_out, int out_size, void* d_ws, size_t ws_size,
                              hipStream_t stream) {
    const float* f_i     = (const float*)d_in[0];
    const float* f_j     = (const float*)d_in[1];
    const float* means   = (const float*)d_in[2];
    const float* scales  = (const float*)d_in[3];
    const float* weights = (const float*)d_in[4];
    float* out = (float*)d_out;

    char* ws = (char*)d_ws;
    __hip_bfloat16* VTT_hi = (__hip_bfloat16*)(ws);            // 64*1024*2 = 128 KB
    __hip_bfloat16* VTT_lo = (__hip_bfloat16*)(ws + 131072);   // 128 KB
    float*          cst    = (float*)(ws + 262144);            // 256 B
    __hip_bfloat16* phi    = (__hip_bfloat16*)(ws + 262400);   // 16384*64*2 = 2 MB

    prep_kernel<<<64, 256, 0, stream>>>(means, scales, VTT_hi, VTT_lo, cst);
    phi_kernel<<<1024, 256, 0, stream>>>(f_i, f_j, VTT_hi, VTT_lo, cst, weights, phi);
    gemm_kernel<<<dim3(64, 64), 256, 0, stream>>>(phi, out);
}

// Round 7
// 328.541 us; speedup vs baseline: 1.0681x; 1.0001x over previous
//
#include <hip/hip_runtime.h>
#include <hip/hip_bf16.h>
#include <math.h>

#define NP   8192
#define CD   512
#define KD   64
#define TWON 16384
#define CC   1024   // virtual contraction: [f | f^2]

typedef __attribute__((ext_vector_type(8))) short short8;
typedef __attribute__((ext_vector_type(4))) float f32x4;

__device__ __forceinline__ void split_bf16(float x, __hip_bfloat16& h, __hip_bfloat16& l) {
    h = __float2bfloat16(x);
    l = __float2bfloat16(x - __bfloat162float(h));
}

// ---------------------------------------------------------------------------
// K0: prep. VTT[k][cc] (bf16 hi/lo), cc<512 -> 2*m*inv2 (pairs with f),
// cc>=512 -> -inv2 (pairs with f^2). cst[k] = sum_c m^2*inv2 (fp32).
// dist[n,k] = sum_cc U[n,cc]*VTT[k,cc] - cst[k],  U = [f | f^2]
// ---------------------------------------------------------------------------
__global__ __launch_bounds__(256) void prep_kernel(
    const float* __restrict__ means, const float* __restrict__ scales,
    __hip_bfloat16* __restrict__ VTT_hi, __hip_bfloat16* __restrict__ VTT_lo,
    float* __restrict__ cst)
{
    const int k = blockIdx.x;
    const int t = threadIdx.x;
    __shared__ float red[256];
    float local = 0.f;
    for (int c = t; c < CD; c += 256) {
        float m    = means[k * CD + c];
        float s    = scales[k * CD + c];
        float inv  = 1.0f / s;
        float inv2 = inv * inv;
        __hip_bfloat16 h, l;
        split_bf16(2.0f * m * inv2, h, l);
        VTT_hi[(size_t)k * CC + c] = h;
        VTT_lo[(size_t)k * CC + c] = l;
        split_bf16(-inv2, h, l);
        VTT_hi[(size_t)k * CC + CD + c] = h;
        VTT_lo[(size_t)k * CC + CD + c] = l;
        local += m * m * inv2;
    }
    red[t] = local;
    __syncthreads();
    for (int off = 128; off > 0; off >>= 1) {
        if (t < off) red[t] += red[t + off];
        __syncthreads();
    }
    if (t == 0) cst[k] = red[0];
}

// ---------------------------------------------------------------------------
// K1: phi bf16 [16384][64] via MFMA, zero LDS. Grid 1024: block = 64 rows x
// 16 k-outs (wave = 16-row m-tile). 4 blocks/CU -> 4 waves/SIMD for latency
// hiding. A = f rows split to bf16 hi/lo in-register (linear + squared),
// B = VTT hi/lo (L2-resident). Compensated: AhBh + AhBl + AlBh.
// ---------------------------------------------------------------------------
__global__ __launch_bounds__(256) void phi_kernel(
    const float* __restrict__ f_i, const float* __restrict__ f_j,
    const __hip_bfloat16* __restrict__ VTT_hi,
    const __hip_bfloat16* __restrict__ VTT_lo,
    const float* __restrict__ cst, const float* __restrict__ weights,
    __hip_bfloat16* __restrict__ phi)
{
    const int t = threadIdx.x, lane = t & 63, wave = t >> 6;
    const int q = lane >> 4, m = lane & 15;
    const int base = (blockIdx.x >> 2) * 64 + wave * 16;  // 16-row m-tile
    const int kt   = (blockIdx.x & 3) * 16;               // 16 k-outs
    const bool iside = (base < NP);                       // uniform per block
    const float* frow = iside ? &f_i[(size_t)(base + m) * CD]
                              : &f_j[(size_t)(base + m - NP) * CD];
    const short* BH = (const short*)VTT_hi;
    const short* BL = (const short*)VTT_lo;

    f32x4 acc = (f32x4){0.f, 0.f, 0.f, 0.f};

    for (int ch = 0; ch < 16; ++ch) {
        const int c0 = ch * 32 + q * 8;
        float4 x0 = *(const float4*)&frow[c0];
        float4 x1 = *(const float4*)&frow[c0 + 4];
        float xs[8] = {x0.x, x0.y, x0.z, x0.w, x1.x, x1.y, x1.z, x1.w};
        union { short8 v; __hip_bfloat16 h[8]; } aLh, aLl, aSh, aSl;
        #pragma unroll
        for (int j = 0; j < 8; ++j) {
            __hip_bfloat16 h, l;
            split_bf16(xs[j], h, l);          aLh.h[j] = h; aLl.h[j] = l;
            split_bf16(xs[j] * xs[j], h, l);  aSh.h[j] = h; aSl.h[j] = l;
        }
        const size_t boff = (size_t)(kt + m) * CC + c0;
        short8 bh0 = *(const short8*)&BH[boff];
        short8 bl0 = *(const short8*)&BL[boff];
        short8 bh1 = *(const short8*)&BH[boff + CD];
        short8 bl1 = *(const short8*)&BL[boff + CD];
        acc = __builtin_amdgcn_mfma_f32_16x16x32_bf16(aLh.v, bh0, acc, 0, 0, 0);
        acc = __builtin_amdgcn_mfma_f32_16x16x32_bf16(aLh.v, bl0, acc, 0, 0, 0);
        acc = __builtin_amdgcn_mfma_f32_16x16x32_bf16(aLl.v, bh0, acc, 0, 0, 0);
        acc = __builtin_amdgcn_mfma_f32_16x16x32_bf16(aSh.v, bh1, acc, 0, 0, 0);
        acc = __builtin_amdgcn_mfma_f32_16x16x32_bf16(aSh.v, bl1, acc, 0, 0, 0);
        acc = __builtin_amdgcn_mfma_f32_16x16x32_bf16(aSl.v, bh1, acc, 0, 0, 0);
    }

    // D layout: row (within m-tile) = q*4+r, col (= k-out) = lane&15 = m
    const int kout = kt + m;
    const float cs = cst[kout];
    const float wv = iside ? weights[kout] : 1.0f;
    #pragma unroll
    for (int r = 0; r < 4; ++r) {
        const int row = base + q * 4 + r;
        float ph = expf(acc[r] - cs) * wv;
        phi[(size_t)row * KD + kout] = __float2bfloat16(ph);
    }
}

// ---------------------------------------------------------------------------
// K2: out = phi_i @ phi_j^T via mfma_f32_16x16x32_bf16. Block 128x128
// (4 waves x 64x64 quadrant), zero LDS in main loop. Epilogue round-trips
// accs through a 64x136 LDS tile (two passes by wave i-parity); global
// stores are 512 B contiguous per row = full 128 B lines, issued
// NONTEMPORAL (ext-vector f32x4 — HIP float4 class is rejected by the
// builtin) to bypass L2 allocation.
// ---------------------------------------------------------------------------
#define LDS_PITCH 136
__global__ __launch_bounds__(256) void gemm_kernel(
    const __hip_bfloat16* __restrict__ phi, float* __restrict__ out)
{
    __shared__ float lds[64 * LDS_PITCH];
    const int t = threadIdx.x, lane = t & 63, wave = t >> 6;
    const int q = lane >> 4, m = lane & 15;
    const int ih = wave & 1, jh = wave >> 1;   // wave's quadrant
    const int i0 = blockIdx.y * 128 + ih * 64;
    const int j0 = blockIdx.x * 128 + jh * 64;
    const short* phiS = (const short*)phi;

    short8 Aj[4][2], Bi[4][2];
    #pragma unroll
    for (int tt = 0; tt < 4; ++tt)
        #pragma unroll
        for (int kh = 0; kh < 2; ++kh) {
            Aj[tt][kh] = *(const short8*)
                &phiS[(size_t)(NP + j0 + tt * 16 + m) * KD + kh * 32 + q * 8];
            Bi[tt][kh] = *(const short8*)
                &phiS[(size_t)(i0 + tt * 16 + m) * KD + kh * 32 + q * 8];
        }

    f32x4 acc[4][4];   // [i-tile][j-tile]
    #pragma unroll
    for (int bt = 0; bt < 4; ++bt)
        #pragma unroll
        for (int at = 0; at < 4; ++at)
            acc[bt][at] = (f32x4){0.f, 0.f, 0.f, 0.f};

    #pragma unroll
    for (int bt = 0; bt < 4; ++bt)
        #pragma unroll
        for (int at = 0; at < 4; ++at) {
            acc[bt][at] = __builtin_amdgcn_mfma_f32_16x16x32_bf16(
                Aj[at][0], Bi[bt][0], acc[bt][at], 0, 0, 0);
            acc[bt][at] = __builtin_amdgcn_mfma_f32_16x16x32_bf16(
                Aj[at][1], Bi[bt][1], acc[bt][at], 0, 0, 0);
        }

    // Epilogue. acc[bt][at][r] = out[i0 + bt*16 + m][j0 + at*16 + q*4 + r].
    const size_t orow0 = (size_t)blockIdx.y * 128;
    const int    ocol0 = blockIdx.x * 128;
    #pragma unroll
    for (int p = 0; p < 2; ++p) {
        __syncthreads();
        if (ih == p) {
            #pragma unroll
            for (int bt = 0; bt < 4; ++bt)
                #pragma unroll
                for (int at = 0; at < 4; ++at)
                    *(f32x4*)&lds[(bt * 16 + m) * LDS_PITCH
                                  + jh * 64 + at * 16 + q * 4] = acc[bt][at];
        }
        __syncthreads();
        #pragma unroll
        for (int it = 0; it < 8; ++it) {
            int v  = t + it * 256;        // 0..2047 float4 slots
            int lr = v >> 5;              // 0..63
            int c4 = (v & 31) * 4;        // 0..124
            f32x4 val = *(const f32x4*)&lds[lr * LDS_PITCH + c4];
            __builtin_nontemporal_store(val,
                (f32x4*)&out[(orow0 + p * 64 + lr) * NP + ocol0 + c4]);
        }
    }
}

// ---------------------------------------------------------------------------
extern "C" void kernel_launch(void* const* d_in, const int* in_sizes, int n_in,
                              void* d_out, int out_size, void* d_ws, size_t ws_size,
                              hipStream_t stream) {
    const float* f_i     = (const float*)d_in[0];
    const float* f_j     = (const float*)d_in[1];
    const float* means   = (const float*)d_in[2];
    const float* scales  = (const float*)d_in[3];
    const float* weights = (const float*)d_in[4];
    float* out = (float*)d_out;

    char* ws = (char*)d_ws;
    __hip_bfloat16* VTT_hi = (__hip_bfloat16*)(ws);            // 64*1024*2 = 128 KB
    __hip_bfloat16* VTT_lo = (__hip_bfloat16*)(ws + 131072);   // 128 KB
    float*          cst    = (float*)(ws + 262144);            // 256 B
    __hip_bfloat16* phi    = (__hip_bfloat16*)(ws + 262400);   // 16384*64*2 = 2 MB

    prep_kernel<<<64, 256, 0, stream>>>(means, scales, VTT_hi, VTT_lo, cst);
    phi_kernel<<<1024, 256, 0, stream>>>(f_i, f_j, VTT_hi, VTT_lo, cst, weights, phi);
    gemm_kernel<<<dim3(64, 64), 256, 0, stream>>>(phi, out);
}

// Round 8
// 324.900 us; speedup vs baseline: 1.0801x; 1.0112x over previous
//
#include <hip/hip_runtime.h>
#include <hip/hip_bf16.h>
#include <math.h>

#define NP   8192
#define CD   512
#define KD   64
#define TWON 16384
#define CC   1024   // virtual contraction: [f | f^2]

typedef __attribute__((ext_vector_type(8))) short short8;
typedef __attribute__((ext_vector_type(4))) float f32x4;

__device__ __forceinline__ void split_bf16(float x, __hip_bfloat16& h, __hip_bfloat16& l) {
    h = __float2bfloat16(x);
    l = __float2bfloat16(x - __bfloat162float(h));
}

// ---------------------------------------------------------------------------
// K0: prep. VTT[k][cc] (bf16 hi/lo), cc<512 -> 2*m*inv2 (pairs with f),
// cc>=512 -> -inv2 (pairs with f^2). cst[k] = sum_c m^2*inv2 (fp32).
// dist[n,k] = sum_cc U[n,cc]*VTT[k,cc] - cst[k],  U = [f | f^2]
// ---------------------------------------------------------------------------
__global__ __launch_bounds__(256) void prep_kernel(
    const float* __restrict__ means, const float* __restrict__ scales,
    __hip_bfloat16* __restrict__ VTT_hi, __hip_bfloat16* __restrict__ VTT_lo,
    float* __restrict__ cst)
{
    const int k = blockIdx.x;
    const int t = threadIdx.x;
    __shared__ float red[256];
    float local = 0.f;
    for (int c = t; c < CD; c += 256) {
        float m    = means[k * CD + c];
        float s    = scales[k * CD + c];
        float inv  = 1.0f / s;
        float inv2 = inv * inv;
        __hip_bfloat16 h, l;
        split_bf16(2.0f * m * inv2, h, l);
        VTT_hi[(size_t)k * CC + c] = h;
        VTT_lo[(size_t)k * CC + c] = l;
        split_bf16(-inv2, h, l);
        VTT_hi[(size_t)k * CC + CD + c] = h;
        VTT_lo[(size_t)k * CC + CD + c] = l;
        local += m * m * inv2;
    }
    red[t] = local;
    __syncthreads();
    for (int off = 128; off > 0; off >>= 1) {
        if (t < off) red[t] += red[t + off];
        __syncthreads();
    }
    if (t == 0) cst[k] = red[0];
}

// ---------------------------------------------------------------------------
// K1: phi bf16 [16384][64] via MFMA, zero LDS. Grid 256: block = 64 rows,
// wave = 16-row m-tile x ALL 64 k-outs (4 acc tiles). f read exactly once
// (vs 4x with the old k-split); 24 MFMA per ch-iter amortizes the hi/lo
// split VALU. B = VTT hi/lo (L2-resident). Compensated: AhBh + AhBl + AlBh.
// ---------------------------------------------------------------------------
__global__ __launch_bounds__(256) void phi_kernel(
    const float* __restrict__ f_i, const float* __restrict__ f_j,
    const __hip_bfloat16* __restrict__ VTT_hi,
    const __hip_bfloat16* __restrict__ VTT_lo,
    const float* __restrict__ cst, const float* __restrict__ weights,
    __hip_bfloat16* __restrict__ phi)
{
    const int t = threadIdx.x, lane = t & 63, wave = t >> 6;
    const int q = lane >> 4, m = lane & 15;
    const int base = blockIdx.x * 64 + wave * 16;   // 16-row m-tile
    const bool iside = (base < NP);                 // uniform per block
    const float* frow = iside ? &f_i[(size_t)(base + m) * CD]
                              : &f_j[(size_t)(base + m - NP) * CD];
    const short* BH = (const short*)VTT_hi;
    const short* BL = (const short*)VTT_lo;

    f32x4 acc[4];
    #pragma unroll
    for (int nt = 0; nt < 4; ++nt) acc[nt] = (f32x4){0.f, 0.f, 0.f, 0.f};

    for (int ch = 0; ch < 16; ++ch) {
        const int c0 = ch * 32 + q * 8;
        float4 x0 = *(const float4*)&frow[c0];
        float4 x1 = *(const float4*)&frow[c0 + 4];
        float xs[8] = {x0.x, x0.y, x0.z, x0.w, x1.x, x1.y, x1.z, x1.w};
        union { short8 v; __hip_bfloat16 h[8]; } aLh, aLl, aSh, aSl;
        #pragma unroll
        for (int j = 0; j < 8; ++j) {
            __hip_bfloat16 h, l;
            split_bf16(xs[j], h, l);          aLh.h[j] = h; aLl.h[j] = l;
            split_bf16(xs[j] * xs[j], h, l);  aSh.h[j] = h; aSl.h[j] = l;
        }
        #pragma unroll
        for (int nt = 0; nt < 4; ++nt) {
            const size_t boff = (size_t)(nt * 16 + m) * CC + c0;
            short8 bh0 = *(const short8*)&BH[boff];
            short8 bl0 = *(const short8*)&BL[boff];
            short8 bh1 = *(const short8*)&BH[boff + CD];
            short8 bl1 = *(const short8*)&BL[boff + CD];
            acc[nt] = __builtin_amdgcn_mfma_f32_16x16x32_bf16(aLh.v, bh0, acc[nt], 0, 0, 0);
            acc[nt] = __builtin_amdgcn_mfma_f32_16x16x32_bf16(aLh.v, bl0, acc[nt], 0, 0, 0);
            acc[nt] = __builtin_amdgcn_mfma_f32_16x16x32_bf16(aLl.v, bh0, acc[nt], 0, 0, 0);
            acc[nt] = __builtin_amdgcn_mfma_f32_16x16x32_bf16(aSh.v, bh1, acc[nt], 0, 0, 0);
            acc[nt] = __builtin_amdgcn_mfma_f32_16x16x32_bf16(aSh.v, bl1, acc[nt], 0, 0, 0);
            acc[nt] = __builtin_amdgcn_mfma_f32_16x16x32_bf16(aSl.v, bh1, acc[nt], 0, 0, 0);
        }
    }

    // D layout: row (within m-tile) = q*4+r, col (= k-out) = lane&15 = m
    #pragma unroll
    for (int nt = 0; nt < 4; ++nt) {
        const int kout = nt * 16 + m;
        const float cs = cst[kout];
        const float wv = iside ? weights[kout] : 1.0f;
        #pragma unroll
        for (int r = 0; r < 4; ++r) {
            const int row = base + q * 4 + r;
            float ph = __expf(acc[nt][r] - cs) * wv;
            phi[(size_t)row * KD + kout] = __float2bfloat16(ph);
        }
    }
}

// ---------------------------------------------------------------------------
// K2: out = phi_i @ phi_j^T via mfma_f32_16x16x32_bf16. Block 128x128
// (4 waves x 64x64 quadrant), zero LDS in main loop. Epilogue round-trips
// accs through a 64x136 LDS tile (two passes by wave i-parity); global
// stores are 512 B contiguous per row = full 128 B lines, issued
// NONTEMPORAL (neutral vs cached — measured R5 vs R7 — kept for fewer
// dirty L2 lines).
// ---------------------------------------------------------------------------
#define LDS_PITCH 136
__global__ __launch_bounds__(256) void gemm_kernel(
    const __hip_bfloat16* __restrict__ phi, float* __restrict__ out)
{
    __shared__ float lds[64 * LDS_PITCH];
    const int t = threadIdx.x, lane = t & 63, wave = t >> 6;
    const int q = lane >> 4, m = lane & 15;
    const int ih = wave & 1, jh = wave >> 1;   // wave's quadrant
    const int i0 = blockIdx.y * 128 + ih * 64;
    const int j0 = blockIdx.x * 128 + jh * 64;
    const short* phiS = (const short*)phi;

    short8 Aj[4][2], Bi[4][2];
    #pragma unroll
    for (int tt = 0; tt < 4; ++tt)
        #pragma unroll
        for (int kh = 0; kh < 2; ++kh) {
            Aj[tt][kh] = *(const short8*)
                &phiS[(size_t)(NP + j0 + tt * 16 + m) * KD + kh * 32 + q * 8];
            Bi[tt][kh] = *(const short8*)
                &phiS[(size_t)(i0 + tt * 16 + m) * KD + kh * 32 + q * 8];
        }

    f32x4 acc[4][4];   // [i-tile][j-tile]
    #pragma unroll
    for (int bt = 0; bt < 4; ++bt)
        #pragma unroll
        for (int at = 0; at < 4; ++at)
            acc[bt][at] = (f32x4){0.f, 0.f, 0.f, 0.f};

    #pragma unroll
    for (int bt = 0; bt < 4; ++bt)
        #pragma unroll
        for (int at = 0; at < 4; ++at) {
            acc[bt][at] = __builtin_amdgcn_mfma_f32_16x16x32_bf16(
                Aj[at][0], Bi[bt][0], acc[bt][at], 0, 0, 0);
            acc[bt][at] = __builtin_amdgcn_mfma_f32_16x16x32_bf16(
                Aj[at][1], Bi[bt][1], acc[bt][at], 0, 0, 0);
        }

    // Epilogue. acc[bt][at][r] = out[i0 + bt*16 + m][j0 + at*16 + q*4 + r].
    const size_t orow0 = (size_t)blockIdx.y * 128;
    const int    ocol0 = blockIdx.x * 128;
    #pragma unroll
    for (int p = 0; p < 2; ++p) {
        __syncthreads();
        if (ih == p) {
            #pragma unroll
            for (int bt = 0; bt < 4; ++bt)
                #pragma unroll
                for (int at = 0; at < 4; ++at)
                    *(f32x4*)&lds[(bt * 16 + m) * LDS_PITCH
                                  + jh * 64 + at * 16 + q * 4] = acc[bt][at];
        }
        __syncthreads();
        #pragma unroll
        for (int it = 0; it < 8; ++it) {
            int v  = t + it * 256;        // 0..2047 float4 slots
            int lr = v >> 5;              // 0..63
            int c4 = (v & 31) * 4;        // 0..124
            f32x4 val = *(const f32x4*)&lds[lr * LDS_PITCH + c4];
            __builtin_nontemporal_store(val,
                (f32x4*)&out[(orow0 + p * 64 + lr) * NP + ocol0 + c4]);
        }
    }
}

// ---------------------------------------------------------------------------
extern "C" void kernel_launch(void* const* d_in, const int* in_sizes, int n_in,
                              void* d_out, int out_size, void* d_ws, size_t ws_size,
                              hipStream_t stream) {
    const float* f_i     = (const float*)d_in[0];
    const float* f_j     = (const float*)d_in[1];
    const float* means   = (const float*)d_in[2];
    const float* scales  = (const float*)d_in[3];
    const float* weights = (const float*)d_in[4];
    float* out = (float*)d_out;

    char* ws = (char*)d_ws;
    __hip_bfloat16* VTT_hi = (__hip_bfloat16*)(ws);            // 64*1024*2 = 128 KB
    __hip_bfloat16* VTT_lo = (__hip_bfloat16*)(ws + 131072);   // 128 KB
    float*          cst    = (float*)(ws + 262144);            // 256 B
    __hip_bfloat16* phi    = (__hip_bfloat16*)(ws + 262400);   // 16384*64*2 = 2 MB

    prep_kernel<<<64, 256, 0, stream>>>(means, scales, VTT_hi, VTT_lo, cst);
    phi_kernel<<<256, 256, 0, stream>>>(f_i, f_j, VTT_hi, VTT_lo, cst, weights, phi);
    gemm_kernel<<<dim3(64, 64), 256, 0, stream>>>(phi, out);
}

// Round 9
// 319.858 us; speedup vs baseline: 1.0971x; 1.0158x over previous
//
#include <hip/hip_runtime.h>
#include <hip/hip_bf16.h>
#include <math.h>

#define NP   8192
#define CD   512
#define KD   64
#define TWON 16384
#define CC   1024   // virtual contraction: [f | f^2]

typedef __attribute__((ext_vector_type(8))) short short8;
typedef __attribute__((ext_vector_type(4))) float f32x4;

// phi layout: fragment-native. Chunk (T, kh), T = 16-row tile in [0,1024),
// kh = k-half in {0,1}; chunk = 512 shorts (1 KB). Element (row, k) with
// row = T*16 + mm, k = kh*32 + qq*8 + jj lives at chunk[(qq*16 + mm)*8 + jj]
// => lane l of a wave reads its 16 B A-frag at chunk + l*16 (coalesced).
#define PHI_CHUNK(T, kh) (((size_t)(T) * 2 + (kh)) * 512)

__device__ __forceinline__ void split_bf16(float x, __hip_bfloat16& h, __hip_bfloat16& l) {
    h = __float2bfloat16(x);
    l = __float2bfloat16(x - __bfloat162float(h));
}

// ---------------------------------------------------------------------------
// K0: prep. VTT[k][cc] (bf16 hi/lo), cc<512 -> 2*m*inv2 (pairs with f),
// cc>=512 -> -inv2 (pairs with f^2). cst[k] = sum_c m^2*inv2 (fp32).
// dist[n,k] = sum_cc U[n,cc]*VTT[k,cc] - cst[k],  U = [f | f^2]
// ---------------------------------------------------------------------------
__global__ __launch_bounds__(256) void prep_kernel(
    const float* __restrict__ means, const float* __restrict__ scales,
    __hip_bfloat16* __restrict__ VTT_hi, __hip_bfloat16* __restrict__ VTT_lo,
    float* __restrict__ cst)
{
    const int k = blockIdx.x;
    const int t = threadIdx.x;
    __shared__ float red[256];
    float local = 0.f;
    for (int c = t; c < CD; c += 256) {
        float m    = means[k * CD + c];
        float s    = scales[k * CD + c];
        float inv  = 1.0f / s;
        float inv2 = inv * inv;
        __hip_bfloat16 h, l;
        split_bf16(2.0f * m * inv2, h, l);
        VTT_hi[(size_t)k * CC + c] = h;
        VTT_lo[(size_t)k * CC + c] = l;
        split_bf16(-inv2, h, l);
        VTT_hi[(size_t)k * CC + CD + c] = h;
        VTT_lo[(size_t)k * CC + CD + c] = l;
        local += m * m * inv2;
    }
    red[t] = local;
    __syncthreads();
    for (int off = 128; off > 0; off >>= 1) {
        if (t < off) red[t] += red[t + off];
        __syncthreads();
    }
    if (t == 0) cst[k] = red[0];
}

// ---------------------------------------------------------------------------
// K1: phi (fragment-native layout) via MFMA. Grid 256: block = 64 rows,
// wave = 16-row m-tile x ALL 64 k-outs (4 acc tiles). Epilogue: per-wave
// LDS transpose (16x72 shorts, 144 B pitch -> bank-clean; no barrier,
// region is wave-private) then 2 coalesced 1 KB chunk stores per wave
// (replaces 16 scattered 2 B stores/lane). Compensated bf16: AhBh+AhBl+AlBh.
// ---------------------------------------------------------------------------
__global__ __launch_bounds__(256) void phi_kernel(
    const float* __restrict__ f_i, const float* __restrict__ f_j,
    const __hip_bfloat16* __restrict__ VTT_hi,
    const __hip_bfloat16* __restrict__ VTT_lo,
    const float* __restrict__ cst, const float* __restrict__ weights,
    short* __restrict__ phiL)
{
    __shared__ short ldsT[4][16][72];   // [wave][row-in-tile][64k + 8 pad]
    const int t = threadIdx.x, lane = t & 63, wave = t >> 6;
    const int q = lane >> 4, m = lane & 15;
    const int base = blockIdx.x * 64 + wave * 16;   // 16-row m-tile
    const bool iside = (base < NP);                 // uniform per block
    const float* frow = iside ? &f_i[(size_t)(base + m) * CD]
                              : &f_j[(size_t)(base + m - NP) * CD];
    const short* BH = (const short*)VTT_hi;
    const short* BL = (const short*)VTT_lo;

    f32x4 acc[4];
    #pragma unroll
    for (int nt = 0; nt < 4; ++nt) acc[nt] = (f32x4){0.f, 0.f, 0.f, 0.f};

    for (int ch = 0; ch < 16; ++ch) {
        const int c0 = ch * 32 + q * 8;
        float4 x0 = *(const float4*)&frow[c0];
        float4 x1 = *(const float4*)&frow[c0 + 4];
        float xs[8] = {x0.x, x0.y, x0.z, x0.w, x1.x, x1.y, x1.z, x1.w};
        union { short8 v; __hip_bfloat16 h[8]; } aLh, aLl, aSh, aSl;
        #pragma unroll
        for (int j = 0; j < 8; ++j) {
            __hip_bfloat16 h, l;
            split_bf16(xs[j], h, l);          aLh.h[j] = h; aLl.h[j] = l;
            split_bf16(xs[j] * xs[j], h, l);  aSh.h[j] = h; aSl.h[j] = l;
        }
        #pragma unroll
        for (int nt = 0; nt < 4; ++nt) {
            const size_t boff = (size_t)(nt * 16 + m) * CC + c0;
            short8 bh0 = *(const short8*)&BH[boff];
            short8 bl0 = *(const short8*)&BL[boff];
            short8 bh1 = *(const short8*)&BH[boff + CD];
            short8 bl1 = *(const short8*)&BL[boff + CD];
            acc[nt] = __builtin_amdgcn_mfma_f32_16x16x32_bf16(aLh.v, bh0, acc[nt], 0, 0, 0);
            acc[nt] = __builtin_amdgcn_mfma_f32_16x16x32_bf16(aLh.v, bl0, acc[nt], 0, 0, 0);
            acc[nt] = __builtin_amdgcn_mfma_f32_16x16x32_bf16(aLl.v, bh0, acc[nt], 0, 0, 0);
            acc[nt] = __builtin_amdgcn_mfma_f32_16x16x32_bf16(aSh.v, bh1, acc[nt], 0, 0, 0);
            acc[nt] = __builtin_amdgcn_mfma_f32_16x16x32_bf16(aSh.v, bl1, acc[nt], 0, 0, 0);
            acc[nt] = __builtin_amdgcn_mfma_f32_16x16x32_bf16(aSl.v, bh1, acc[nt], 0, 0, 0);
        }
    }

    // Epilogue: exp + bf16, dump to wave-private LDS tile [row][k].
    // D layout: row (within m-tile) = q*4+r, col (= k-out) = nt*16+m.
    #pragma unroll
    for (int nt = 0; nt < 4; ++nt) {
        const int kout = nt * 16 + m;
        const float cs = cst[kout];
        const float wv = iside ? weights[kout] : 1.0f;
        #pragma unroll
        for (int r = 0; r < 4; ++r) {
            float ph = __expf(acc[nt][r] - cs) * wv;
            __hip_bfloat16 b = __float2bfloat16(ph);
            ldsT[wave][q * 4 + r][kout] = *(short*)&b;
        }
    }
    // Coalesced chunk stores: lane l -> chunk + l*8 shorts (16 B).
    const int T = blockIdx.x * 4 + wave;   // global 16-row tile index
    #pragma unroll
    for (int kh = 0; kh < 2; ++kh) {
        short8 v = *(const short8*)&ldsT[wave][m][kh * 32 + q * 8];
        *(short8*)&phiL[PHI_CHUNK(T, kh) + lane * 8] = v;
    }
}

// ---------------------------------------------------------------------------
// K2: out = phi_i @ phi_j^T via mfma_f32_16x16x32_bf16. Block 128x128
// (4 waves x 64x64 quadrant). phi is fragment-native so every A/B-frag load
// is one fully-coalesced dwordx4 (was: 16-row gather = 16 transactions).
// Epilogue round-trips accs through a 64x136 LDS tile (two passes by wave
// i-parity); global stores are full 128 B lines, nontemporal.
// ---------------------------------------------------------------------------
#define LDS_PITCH 136
__global__ __launch_bounds__(256) void gemm_kernel(
    const short* __restrict__ phiL, float* __restrict__ out)
{
    __shared__ float lds[64 * LDS_PITCH];
    const int t = threadIdx.x, lane = t & 63, wave = t >> 6;
    const int q = lane >> 4, m = lane & 15;
    const int ih = wave & 1, jh = wave >> 1;   // wave's quadrant
    const int i0 = blockIdx.y * 128 + ih * 64;
    const int j0 = blockIdx.x * 128 + jh * 64;
    const int iT = i0 >> 4;                    // first i row-tile
    const int jT = (NP + j0) >> 4;             // first j row-tile

    short8 Aj[4][2], Bi[4][2];
    #pragma unroll
    for (int tt = 0; tt < 4; ++tt)
        #pragma unroll
        for (int kh = 0; kh < 2; ++kh) {
            Aj[tt][kh] = *(const short8*)&phiL[PHI_CHUNK(jT + tt, kh) + lane * 8];
            Bi[tt][kh] = *(const short8*)&phiL[PHI_CHUNK(iT + tt, kh) + lane * 8];
        }

    f32x4 acc[4][4];   // [i-tile][j-tile]
    #pragma unroll
    for (int bt = 0; bt < 4; ++bt)
        #pragma unroll
        for (int at = 0; at < 4; ++at)
            acc[bt][at] = (f32x4){0.f, 0.f, 0.f, 0.f};

    #pragma unroll
    for (int bt = 0; bt < 4; ++bt)
        #pragma unroll
        for (int at = 0; at < 4; ++at) {
            acc[bt][at] = __builtin_amdgcn_mfma_f32_16x16x32_bf16(
                Aj[at][0], Bi[bt][0], acc[bt][at], 0, 0, 0);
            acc[bt][at] = __builtin_amdgcn_mfma_f32_16x16x32_bf16(
                Aj[at][1], Bi[bt][1], acc[bt][at], 0, 0, 0);
        }

    // Epilogue. acc[bt][at][r] = out[i0 + bt*16 + m][j0 + at*16 + q*4 + r].
    const size_t orow0 = (size_t)blockIdx.y * 128;
    const int    ocol0 = blockIdx.x * 128;
    #pragma unroll
    for (int p = 0; p < 2; ++p) {
        __syncthreads();
        if (ih == p) {
            #pragma unroll
            for (int bt = 0; bt < 4; ++bt)
                #pragma unroll
                for (int at = 0; at < 4; ++at)
                    *(f32x4*)&lds[(bt * 16 + m) * LDS_PITCH
                                  + jh * 64 + at * 16 + q * 4] = acc[bt][at];
        }
        __syncthreads();
        #pragma unroll
        for (int it = 0; it < 8; ++it) {
            int v  = t + it * 256;        // 0..2047 float4 slots
            int lr = v >> 5;              // 0..63
            int c4 = (v & 31) * 4;        // 0..124
            f32x4 val = *(const f32x4*)&lds[lr * LDS_PITCH + c4];
            __builtin_nontemporal_store(val,
                (f32x4*)&out[(orow0 + p * 64 + lr) * NP + ocol0 + c4]);
        }
    }
}

// ---------------------------------------------------------------------------
extern "C" void kernel_launch(void* const* d_in, const int* in_sizes, int n_in,
                              void* d_out, int out_size, void* d_ws, size_t ws_size,
                              hipStream_t stream) {
    const float* f_i     = (const float*)d_in[0];
    const float* f_j     = (const float*)d_in[1];
    const float* means   = (const float*)d_in[2];
    const float* scales  = (const float*)d_in[3];
    const float* weights = (const float*)d_in[4];
    float* out = (float*)d_out;

    char* ws = (char*)d_ws;
    __hip_bfloat16* VTT_hi = (__hip_bfloat16*)(ws);            // 64*1024*2 = 128 KB
    __hip_bfloat16* VTT_lo = (__hip_bfloat16*)(ws + 131072);   // 128 KB
    float*          cst    = (float*)(ws + 262144);            // 256 B
    short*          phiL   = (short*)(ws + 262400);            // 2 MB frag-native

    prep_kernel<<<64, 256, 0, stream>>>(means, scales, VTT_hi, VTT_lo, cst);
    phi_kernel<<<256, 256, 0, stream>>>(f_i, f_j, VTT_hi, VTT_lo, cst, weights, phiL);
    gemm_kernel<<<dim3(64, 64), 256, 0, stream>>>(phiL, out);
}

// Round 11
// 319.016 us; speedup vs baseline: 1.1000x; 1.0026x over previous
//
#include <hip/hip_runtime.h>
#include <hip/hip_bf16.h>
#include <math.h>

#define NP   8192
#define CD   512
#define KD   64
#define TWON 16384
#define CC   1024   // virtual contraction: [f | f^2]

typedef __attribute__((ext_vector_type(8))) short short8;
typedef __attribute__((ext_vector_type(4))) float f32x4;

// phi layout: fragment-native. Chunk (T, kh), T = 16-row tile in [0,1024),
// kh = k-half in {0,1}; chunk = 512 shorts (1 KB). Element (row, k) with
// row = T*16 + mm, k = kh*32 + qq*8 + jj lives at chunk[(qq*16 + mm)*8 + jj]
// => lane l of a wave reads its 16 B A-frag at chunk + l*16 (coalesced).
#define PHI_CHUNK(T, kh) (((size_t)(T) * 2 + (kh)) * 512)

__device__ __forceinline__ void split_bf16(float x, __hip_bfloat16& h, __hip_bfloat16& l) {
    h = __float2bfloat16(x);
    l = __float2bfloat16(x - __bfloat162float(h));
}

// ---------------------------------------------------------------------------
// K0: prep. VTT[k][cc] (bf16 hi/lo), cc<512 -> 2*m*inv2 (pairs with f),
// cc>=512 -> -inv2 (pairs with f^2). cst[k] = sum_c m^2*inv2 (fp32).
// dist[n,k] = sum_cc U[n,cc]*VTT[k,cc] - cst[k],  U = [f | f^2]
// ---------------------------------------------------------------------------
__global__ __launch_bounds__(256) void prep_kernel(
    const float* __restrict__ means, const float* __restrict__ scales,
    __hip_bfloat16* __restrict__ VTT_hi, __hip_bfloat16* __restrict__ VTT_lo,
    float* __restrict__ cst)
{
    const int k = blockIdx.x;
    const int t = threadIdx.x;
    __shared__ float red[256];
    float local = 0.f;
    for (int c = t; c < CD; c += 256) {
        float m    = means[k * CD + c];
        float s    = scales[k * CD + c];
        float inv  = 1.0f / s;
        float inv2 = inv * inv;
        __hip_bfloat16 h, l;
        split_bf16(2.0f * m * inv2, h, l);
        VTT_hi[(size_t)k * CC + c] = h;
        VTT_lo[(size_t)k * CC + c] = l;
        split_bf16(-inv2, h, l);
        VTT_hi[(size_t)k * CC + CD + c] = h;
        VTT_lo[(size_t)k * CC + CD + c] = l;
        local += m * m * inv2;
    }
    red[t] = local;
    __syncthreads();
    for (int off = 128; off > 0; off >>= 1) {
        if (t < off) red[t] += red[t + off];
        __syncthreads();
    }
    if (t == 0) cst[k] = red[0];
}

// ---------------------------------------------------------------------------
// K1: phi (fragment-native layout) via MFMA. Grid 256: block = 64 rows,
// wave = 16-row m-tile x ALL 64 k-outs (4 acc tiles). K1 runs at 1 wave/SIMD
// so the f-load chain is latency-exposed: SOFTWARE-PIPELINE the f loads
// (prefetch ch+1 before consuming ch). Epilogue: per-wave LDS transpose then
// 2 coalesced 1 KB chunk stores per wave. Compensated bf16: AhBh+AhBl+AlBh.
// ---------------------------------------------------------------------------
__global__ __launch_bounds__(256) void phi_kernel(
    const float* __restrict__ f_i, const float* __restrict__ f_j,
    const __hip_bfloat16* __restrict__ VTT_hi,
    const __hip_bfloat16* __restrict__ VTT_lo,
    const float* __restrict__ cst, const float* __restrict__ weights,
    short* __restrict__ phiL)
{
    __shared__ short ldsT[4][16][72];   // [wave][row-in-tile][64k + 8 pad]
    const int t = threadIdx.x, lane = t & 63, wave = t >> 6;
    const int q = lane >> 4, m = lane & 15;
    const int base = blockIdx.x * 64 + wave * 16;   // 16-row m-tile
    const bool iside = (base < NP);                 // uniform per block
    const float* frow = iside ? &f_i[(size_t)(base + m) * CD]
                              : &f_j[(size_t)(base + m - NP) * CD];
    const short* BH = (const short*)VTT_hi;
    const short* BL = (const short*)VTT_lo;

    f32x4 acc[4];
    #pragma unroll
    for (int nt = 0; nt < 4; ++nt) acc[nt] = (f32x4){0.f, 0.f, 0.f, 0.f};

    // Software pipeline: x0/x1 hold chunk ch; prefetch ch+1 before compute.
    float4 x0 = *(const float4*)&frow[q * 8];
    float4 x1 = *(const float4*)&frow[q * 8 + 4];
    for (int ch = 0; ch < 16; ++ch) {
        float4 nx0, nx1;
        if (ch < 15) {
            const int cn = (ch + 1) * 32 + q * 8;
            nx0 = *(const float4*)&frow[cn];
            nx1 = *(const float4*)&frow[cn + 4];
        }
        const int c0 = ch * 32 + q * 8;
        float xs[8] = {x0.x, x0.y, x0.z, x0.w, x1.x, x1.y, x1.z, x1.w};
        union { short8 v; __hip_bfloat16 h[8]; } aLh, aLl, aSh, aSl;
        #pragma unroll
        for (int j = 0; j < 8; ++j) {
            __hip_bfloat16 h, l;
            split_bf16(xs[j], h, l);          aLh.h[j] = h; aLl.h[j] = l;
            split_bf16(xs[j] * xs[j], h, l);  aSh.h[j] = h; aSl.h[j] = l;
        }
        #pragma unroll
        for (int nt = 0; nt < 4; ++nt) {
            const size_t boff = (size_t)(nt * 16 + m) * CC + c0;
            short8 bh0 = *(const short8*)&BH[boff];
            short8 bl0 = *(const short8*)&BL[boff];
            short8 bh1 = *(const short8*)&BH[boff + CD];
            short8 bl1 = *(const short8*)&BL[boff + CD];
            acc[nt] = __builtin_amdgcn_mfma_f32_16x16x32_bf16(aLh.v, bh0, acc[nt], 0, 0, 0);
            acc[nt] = __builtin_amdgcn_mfma_f32_16x16x32_bf16(aLh.v, bl0, acc[nt], 0, 0, 0);
            acc[nt] = __builtin_amdgcn_mfma_f32_16x16x32_bf16(aLl.v, bh0, acc[nt], 0, 0, 0);
            acc[nt] = __builtin_amdgcn_mfma_f32_16x16x32_bf16(aSh.v, bh1, acc[nt], 0, 0, 0);
            acc[nt] = __builtin_amdgcn_mfma_f32_16x16x32_bf16(aSh.v, bl1, acc[nt], 0, 0, 0);
            acc[nt] = __builtin_amdgcn_mfma_f32_16x16x32_bf16(aSl.v, bh1, acc[nt], 0, 0, 0);
        }
        x0 = nx0; x1 = nx1;
    }

    // Epilogue: exp + bf16, dump to wave-private LDS tile [row][k].
    // D layout: row (within m-tile) = q*4+r, col (= k-out) = nt*16+m.
    #pragma unroll
    for (int nt = 0; nt < 4; ++nt) {
        const int kout = nt * 16 + m;
        const float cs = cst[kout];
        const float wv = iside ? weights[kout] : 1.0f;
        #pragma unroll
        for (int r = 0; r < 4; ++r) {
            float ph = __expf(acc[nt][r] - cs) * wv;
            __hip_bfloat16 b = __float2bfloat16(ph);
            ldsT[wave][q * 4 + r][kout] = *(short*)&b;
        }
    }
    // Coalesced chunk stores: lane l -> chunk + l*8 shorts (16 B).
    const int T = blockIdx.x * 4 + wave;   // global 16-row tile index
    #pragma unroll
    for (int kh = 0; kh < 2; ++kh) {
        short8 v = *(const short8*)&ldsT[wave][m][kh * 32 + q * 8];
        *(short8*)&phiL[PHI_CHUNK(T, kh) + lane * 8] = v;
    }
}

// ---------------------------------------------------------------------------
// K2: out = phi_i @ phi_j^T via mfma_f32_16x16x32_bf16. Block 128x128
// (4 waves x 64x64 quadrant). phi is fragment-native so every A/B-frag load
// is one fully-coalesced dwordx4. Epilogue round-trips accs through a
// 64x136 LDS tile (two passes by wave i-parity); global stores are full
// 128 B lines, nontemporal. At the HBM-write floor (~45 us).
// ---------------------------------------------------------------------------
#define LDS_PITCH 136
__global__ __launch_bounds__(256) void gemm_kernel(
    const short* __restrict__ phiL, float* __restrict__ out)
{
    __shared__ float lds[64 * LDS_PITCH];
    const int t = threadIdx.x, lane = t & 63, wave = t >> 6;
    const int q = lane >> 4, m = lane & 15;
    const int ih = wave & 1, jh = wave >> 1;   // wave's quadrant
    const int i0 = blockIdx.y * 128 + ih * 64;
    const int j0 = blockIdx.x * 128 + jh * 64;
    const int iT = i0 >> 4;                    // first i row-tile
    const int jT = (NP + j0) >> 4;             // first j row-tile

    short8 Aj[4][2], Bi[4][2];
    #pragma unroll
    for (int tt = 0; tt < 4; ++tt)
        #pragma unroll
        for (int kh = 0; kh < 2; ++kh) {
            Aj[tt][kh] = *(const short8*)&phiL[PHI_CHUNK(jT + tt, kh) + lane * 8];
            Bi[tt][kh] = *(const short8*)&phiL[PHI_CHUNK(iT + tt, kh) + lane * 8];
        }

    f32x4 acc[4][4];   // [i-tile][j-tile]
    #pragma unroll
    for (int bt = 0; bt < 4; ++bt)
        #pragma unroll
        for (int at = 0; at < 4; ++at)
            acc[bt][at] = (f32x4){0.f, 0.f, 0.f, 0.f};

    #pragma unroll
    for (int bt = 0; bt < 4; ++bt)
        #pragma unroll
        for (int at = 0; at < 4; ++at) {
            acc[bt][at] = __builtin_amdgcn_mfma_f32_16x16x32_bf16(
                Aj[at][0], Bi[bt][0], acc[bt][at], 0, 0, 0);
            acc[bt][at] = __builtin_amdgcn_mfma_f32_16x16x32_bf16(
                Aj[at][1], Bi[bt][1], acc[bt][at], 0, 0, 0);
        }

    // Epilogue. acc[bt][at][r] = out[i0 + bt*16 + m][j0 + at*16 + q*4 + r].
    const size_t orow0 = (size_t)blockIdx.y * 128;
    const int    ocol0 = blockIdx.x * 128;
    #pragma unroll
    for (int p = 0; p < 2; ++p) {
        __syncthreads();
        if (ih == p) {
            #pragma unroll
            for (int bt = 0; bt < 4; ++bt)
                #pragma unroll
                for (int at = 0; at < 4; ++at)
                    *(f32x4*)&lds[(bt * 16 + m) * LDS_PITCH
                                  + jh * 64 + at * 16 + q * 4] = acc[bt][at];
        }
        __syncthreads();
        #pragma unroll
        for (int it = 0; it < 8; ++it) {
            int v  = t + it * 256;        // 0..2047 float4 slots
            int lr = v >> 5;              // 0..63
            int c4 = (v & 31) * 4;        // 0..124
            f32x4 val = *(const f32x4*)&lds[lr * LDS_PITCH + c4];
            __builtin_nontemporal_store(val,
                (f32x4*)&out[(orow0 + p * 64 + lr) * NP + ocol0 + c4]);
        }
    }
}

// ---------------------------------------------------------------------------
extern "C" void kernel_launch(void* const* d_in, const int* in_sizes, int n_in,
                              void* d_out, int out_size, void* d_ws, size_t ws_size,
                              hipStream_t stream) {
    const float* f_i     = (const float*)d_in[0];
    const float* f_j     = (const float*)d_in[1];
    const float* means   = (const float*)d_in[2];
    const float* scales  = (const float*)d_in[3];
    const float* weights = (const float*)d_in[4];
    float* out = (float*)d_out;

    char* ws = (char*)d_ws;
    __hip_bfloat16* VTT_hi = (__hip_bfloat16*)(ws);            // 64*1024*2 = 128 KB
    __hip_bfloat16* VTT_lo = (__hip_bfloat16*)(ws + 131072);   // 128 KB
    float*          cst    = (float*)(ws + 262144);            // 256 B
    short*          phiL   = (short*)(ws + 262400);            // 2 MB frag-native

    prep_kernel<<<64, 256, 0, stream>>>(means, scales, VTT_hi, VTT_lo, cst);
    phi_kernel<<<256, 256, 0, stream>>>(f_i, f_j, VTT_hi, VTT_lo, cst, weights, phiL);
    gemm_kernel<<<dim3(64, 64), 256, 0, stream>>>(phiL, out);
}